// Round 2
// baseline (81.444 us; speedup 1.0000x reference)
//
#include <hip/hip_runtime.h>

#define N 8192
#define BLOCK 256
#define IPB 8            // i-bodies per block = BLOCK / 32
#define CHUNK 2048       // j-bodies per LDS stage (32 KB -> 4 blocks/CU)
#define SOFT2 1.0e-4f    // 0.01^2

// One block owns IPB i-bodies outright: thread t = (il<<5)|jl accumulates
// pairs (i = blockIdx*IPB + il, j = jl + 32k), then a width-32 shuffle
// reduction folds the 32 j-lane partials. No atomics, no output memset,
// single dispatch. 1024 blocks x 4 waves = 16 waves/CU.
__global__ __launch_bounds__(BLOCK) void nbody_kernel(
    const float* __restrict__ pos, const float* __restrict__ mass,
    float* __restrict__ out) {
  __shared__ float4 tile[CHUNK];

  const int t = threadIdx.x;
  const int jl = t & 31;   // j lane within the 32-wide group
  const int il = t >> 5;   // which of the block's 8 i-bodies
  const int i = blockIdx.x * IPB + il;

  const float xi = pos[i * 3 + 0];
  const float yi = pos[i * 3 + 1];
  const float zi = pos[i * 3 + 2];

  float ax = 0.f, ay = 0.f, az = 0.f;

  for (int c0 = 0; c0 < N; c0 += CHUNK) {
    __syncthreads();  // previous chunk fully consumed before overwrite
    for (int s = t; s < CHUNK; s += BLOCK) {
      const int j = c0 + s;
      tile[s] = make_float4(pos[j * 3 + 0], pos[j * 3 + 1], pos[j * 3 + 2],
                            mass[j]);
    }
    __syncthreads();

    // lanes 0-31 read stride-16B (conflict-free); lanes 32-63 read the same
    // addresses (broadcast, free) -> LDS traffic halved per pair.
#pragma unroll 8
    for (int k = jl; k < CHUNK; k += 32) {
      float4 o = tile[k];
      float dx = o.x - xi;
      float dy = o.y - yi;
      float dz = o.z - zi;
      float r2 = fmaf(dx, dx, fmaf(dy, dy, fmaf(dz, dz, SOFT2)));
      float inv = __builtin_amdgcn_rsqf(r2);  // v_rsq_f32
      float inv2 = inv * inv;
      float w = o.w * (inv2 * inv);           // m_j * r^-3
      ax = fmaf(w, dx, ax);
      ay = fmaf(w, dy, ay);
      az = fmaf(w, dz, az);
    }
  }

  // Reduce the 32 j-lane partials (they live in one 32-lane shuffle group).
#pragma unroll
  for (int off = 16; off > 0; off >>= 1) {
    ax += __shfl_down(ax, off, 32);
    ay += __shfl_down(ay, off, 32);
    az += __shfl_down(az, off, 32);
  }

  if (jl == 0) {
    out[i * 3 + 0] = ax;
    out[i * 3 + 1] = ay;
    out[i * 3 + 2] = az;
  }
}

extern "C" void kernel_launch(void* const* d_in, const int* in_sizes, int n_in,
                              void* d_out, int out_size, void* d_ws,
                              size_t ws_size, hipStream_t stream) {
  const float* pos = (const float*)d_in[0];
  const float* mass = (const float*)d_in[1];
  float* out = (float*)d_out;
  nbody_kernel<<<dim3(N / IPB), BLOCK, 0, stream>>>(pos, mass, out);
}